// Round 3
// baseline (502.421 us; speedup 1.0000x reference)
//
#include <hip/hip_runtime.h>

#define NSEG 16
#define OUT_COLS 384                 // 256 coarse + 128 fine
#define FINE_ITERS 32
#define COARSE_ITERS 16

// ---------------------------------------------------------------------------
// Main streaming kernel. Each block owns a contiguous chunk of one input
// (fine: 32 iters x 256 float4 = 128KB = 256 rows; coarse: 16 iters = 64KB =
// 64 rows). Min segment length (682 coarse / 10922 fine rows) >> block window,
// so each window crosses AT MOST ONE segment boundary. The boundary row is
// block-uniform; each thread precomputes its crossing iteration iCross and
// accumulates into acc0 (seg s0) / acc1 (seg s0+1) with branch-free selects,
// so the fully-unrolled loop is pure load+VALU -> deep load pipelining
// (R2 post-mortem: runtime-bounded loop kept VGPRs at ~12, loads serialized).
// Epilogue: LDS reduction across the 8 (fine) / 4 (coarse) threads sharing a
// column group, then ONE non-atomic coalesced write of [2][D] partials into a
// per-block ws slot (R2 post-mortem #2: ~3M global fp32 atomics suspected).
// ---------------------------------------------------------------------------

template <int ITERS, int ROWSHIFT, int COLMASK, int DLOC>
__device__ __forceinline__ void run_side(
    const float4* __restrict__ src, int blockLocal,
    const int* s_cum, const float* s_inv,
    float* __restrict__ wsSlot,   // 2*DLOC floats, private to this block
    float* __restrict__ lds)      // 2048 floats scratch
{
    const int t = threadIdx.x;
    const int idx0 = blockLocal * (256 * ITERS) + t;       // float4 index

    // block-uniform first segment + boundary row
    const int firstRow = (blockLocal * (256 * ITERS)) >> ROWSHIFT;
    int s0 = 0;
    while (firstRow >= s_cum[s0]) ++s0;
    const int bRow = s_cum[s0];                            // end row of seg s0

    // smallest i with (idx0 + i*256) >> ROWSHIFT >= bRow
    int iCross = ((bRow << ROWSHIFT) - idx0 + 255) >> 8;
    if (iCross < 0) iCross = 0;
    if (iCross > ITERS) iCross = ITERS;

    float4 acc0 = make_float4(0.f, 0.f, 0.f, 0.f);
    float4 acc1 = make_float4(0.f, 0.f, 0.f, 0.f);
    #pragma unroll 16
    for (int i = 0; i < ITERS; ++i) {
        const float4 v = src[idx0 + (i << 8)];
        const bool p = (i < iCross);
        acc0.x += p ? v.x : 0.f;  acc1.x += p ? 0.f : v.x;
        acc0.y += p ? v.y : 0.f;  acc1.y += p ? 0.f : v.y;
        acc0.z += p ? v.z : 0.f;  acc1.z += p ? 0.f : v.z;
        acc0.w += p ? v.w : 0.f;  acc1.w += p ? 0.f : v.w;
    }

    // stash per-thread partials
    float4* l0 = (float4*)lds;          // 256 float4
    float4* l1 = (float4*)(lds + 1024); // 256 float4
    l0[t] = acc0;
    l1[t] = acc1;
    __syncthreads();

    // gather across the 256/(COLMASK+1) threads sharing each column group
    if (t <= COLMASK) {
        const float inv0 = s_inv[s0];
        const float inv1 = s_inv[(s0 < NSEG - 1) ? s0 + 1 : s0];
        float4 r0 = make_float4(0.f, 0.f, 0.f, 0.f);
        float4 r1 = make_float4(0.f, 0.f, 0.f, 0.f);
        #pragma unroll
        for (int k = 0; k < 256 / (COLMASK + 1); ++k) {
            const int tt = t + (COLMASK + 1) * k;
            const float4 a = l0[tt];
            const float4 b = l1[tt];
            r0.x += a.x; r0.y += a.y; r0.z += a.z; r0.w += a.w;
            r1.x += b.x; r1.y += b.y; r1.z += b.z; r1.w += b.w;
        }
        r0.x *= inv0; r0.y *= inv0; r0.z *= inv0; r0.w *= inv0;
        r1.x *= inv1; r1.y *= inv1; r1.z *= inv1; r1.w *= inv1;
        ((float4*)wsSlot)[t] = r0;                 // slot0: seg s0
        ((float4*)(wsSlot + DLOC))[t] = r1;        // slot1: seg s0+1
    }
}

__global__ __launch_bounds__(256) void seg_mean_kernel(
    const float4* __restrict__ ff, const float4* __restrict__ fc,
    const int* __restrict__ len_f, const int* __restrict__ len_c,
    float* __restrict__ ws, int fineBlocks)
{
    __shared__ int   s_cum[NSEG];
    __shared__ float s_inv[NSEG];
    __shared__ float lds[2048];
    const bool fine = (int)blockIdx.x < fineBlocks;
    const int* len = fine ? len_f : len_c;
    if (threadIdx.x == 0) {
        int c = 0;
        for (int i = 0; i < NSEG; ++i) {
            int l = len[i];
            c += l;
            s_cum[i] = c;
            s_inv[i] = 1.0f / (float)l;
        }
    }
    __syncthreads();

    if (fine) {
        const int b = (int)blockIdx.x;
        run_side<FINE_ITERS, 5, 31, 128>(ff, b, s_cum, s_inv, ws + b * 256, lds);
    } else {
        const int b = (int)blockIdx.x - fineBlocks;
        run_side<COARSE_ITERS, 6, 63, 256>(fc, b, s_cum, s_inv,
                                           ws + fineBlocks * 256 + b * 512, lds);
    }
}

// ---------------------------------------------------------------------------
// Deterministic slot reduction. Blocks 0..15: fine seg s -> out cols 256..383;
// blocks 16..31: coarse seg s -> out cols 0..255. Each thread owns one column
// and walks only the blocks whose window can touch seg s (firstRow in
// [cum[s-2], cum[s]) ), tracking the block's s0 incrementally (non-decreasing).
// Writes every d_out element (harness poisons d_out to 0xAA each call).
// ---------------------------------------------------------------------------
__global__ __launch_bounds__(256) void reduce_kernel(
    const float* __restrict__ ws,
    const int* __restrict__ len_f, const int* __restrict__ len_c,
    float* __restrict__ out, int fineBlocks, int coarseBlocks)
{
    __shared__ int cum[NSEG];
    const bool fine = (int)blockIdx.x < NSEG;
    const int seg = (int)blockIdx.x & 15;
    const int* len = fine ? len_f : len_c;
    if (threadIdx.x == 0) {
        int c = 0;
        for (int i = 0; i < NSEG; ++i) { c += len[i]; cum[i] = c; }
    }
    __syncthreads();

    const int D = fine ? 128 : 256;
    const int c = threadIdx.x;
    if (c >= D) return;

    const float* base = fine ? ws : ws + fineBlocks * 256;
    const int shift = fine ? 8 : 6;            // rows per block = 256 / 64
    const int nb = fine ? fineBlocks : coarseBlocks;
    const int slotSize = 2 * D;

    const int cumM2 = (seg >= 2) ? cum[seg - 2] : 0;
    int bStart = (cumM2 + (1 << shift) - 1) >> shift;
    int bEnd = (cum[seg] - 1) >> shift;
    if (bEnd > nb - 1) bEnd = nb - 1;

    float acc = 0.f;
    int s0 = 0;
    for (int b = bStart; b <= bEnd; ++b) {
        const int firstRow = b << shift;
        while (firstRow >= cum[s0]) ++s0;
        if (s0 > seg) break;
        if (s0 == seg)          acc += base[b * slotSize + c];
        else if (s0 + 1 == seg) acc += base[b * slotSize + D + c];
    }
    out[seg * OUT_COLS + (fine ? 256 + c : c)] = acc;
}

extern "C" void kernel_launch(void* const* d_in, const int* in_sizes, int n_in,
                              void* d_out, int out_size, void* d_ws, size_t ws_size,
                              hipStream_t stream) {
    const float4* ff = (const float4*)d_in[0];   // feats_f [524288,128] f32
    const float4* fc = (const float4*)d_in[1];   // feats_c [32768,256]  f32
    const int* lf = (const int*)d_in[2];         // lengths_f [16] i32
    const int* lc = (const int*)d_in[3];         // lengths_c [16] i32
    float* out = (float*)d_out;                  // [16,384] f32

    const int NF4 = in_sizes[0] / 4;             // 16,777,216 float4
    const int NC4 = in_sizes[1] / 4;             //  2,097,152 float4
    const int fineBlocks   = NF4 / (256 * FINE_ITERS);    // 2048
    const int coarseBlocks = NC4 / (256 * COARSE_ITERS);  // 512

    seg_mean_kernel<<<fineBlocks + coarseBlocks, 256, 0, stream>>>(
        ff, fc, lf, lc, (float*)d_ws, fineBlocks);

    reduce_kernel<<<2 * NSEG, 256, 0, stream>>>(
        (const float*)d_ws, lf, lc, out, fineBlocks, coarseBlocks);
}

// Round 4
// 465.119 us; speedup vs baseline: 1.0802x; 1.0802x over previous
//
#include <hip/hip_runtime.h>

#define NSEG 16
#define OUT_COLS 384                 // 256 coarse + 128 fine
#define FINE_ITERS 32
#define COARSE_ITERS 16

// ---------------------------------------------------------------------------
// Streaming kernel (unchanged structure from R3, unroll 16->8). Each block
// owns a contiguous chunk (fine: 256 rows, coarse: 64 rows). Min segment
// length (682 coarse / 10922 fine rows) >> window, so each window crosses at
// most ONE boundary. Branch-free dual-accumulator loop -> deep load
// pipelining; LDS epilogue; ONE non-atomic slot write per block.
// ---------------------------------------------------------------------------
template <int ITERS, int ROWSHIFT, int COLMASK, int DLOC>
__device__ __forceinline__ void run_side(
    const float4* __restrict__ src, int blockLocal,
    const int* s_cum, const float* s_inv,
    float* __restrict__ wsSlot,   // 2*DLOC floats, private to this block
    float* __restrict__ lds)      // 2048 floats scratch
{
    const int t = threadIdx.x;
    const int idx0 = blockLocal * (256 * ITERS) + t;       // float4 index

    const int firstRow = (blockLocal * (256 * ITERS)) >> ROWSHIFT;
    int s0 = 0;
    while (firstRow >= s_cum[s0]) ++s0;
    const int bRow = s_cum[s0];                            // end row of seg s0

    int iCross = ((bRow << ROWSHIFT) - idx0 + 255) >> 8;   // first i past bRow
    if (iCross < 0) iCross = 0;
    if (iCross > ITERS) iCross = ITERS;

    float4 acc0 = make_float4(0.f, 0.f, 0.f, 0.f);
    float4 acc1 = make_float4(0.f, 0.f, 0.f, 0.f);
    #pragma unroll 8
    for (int i = 0; i < ITERS; ++i) {
        const float4 v = src[idx0 + (i << 8)];
        const bool p = (i < iCross);
        acc0.x += p ? v.x : 0.f;  acc1.x += p ? 0.f : v.x;
        acc0.y += p ? v.y : 0.f;  acc1.y += p ? 0.f : v.y;
        acc0.z += p ? v.z : 0.f;  acc1.z += p ? 0.f : v.z;
        acc0.w += p ? v.w : 0.f;  acc1.w += p ? 0.f : v.w;
    }

    float4* l0 = (float4*)lds;          // 256 float4
    float4* l1 = (float4*)(lds + 1024); // 256 float4
    l0[t] = acc0;
    l1[t] = acc1;
    __syncthreads();

    if (t <= COLMASK) {
        const float inv0 = s_inv[s0];
        const float inv1 = s_inv[(s0 < NSEG - 1) ? s0 + 1 : s0];
        float4 r0 = make_float4(0.f, 0.f, 0.f, 0.f);
        float4 r1 = make_float4(0.f, 0.f, 0.f, 0.f);
        #pragma unroll
        for (int k = 0; k < 256 / (COLMASK + 1); ++k) {
            const int tt = t + (COLMASK + 1) * k;
            const float4 a = l0[tt];
            const float4 b = l1[tt];
            r0.x += a.x; r0.y += a.y; r0.z += a.z; r0.w += a.w;
            r1.x += b.x; r1.y += b.y; r1.z += b.z; r1.w += b.w;
        }
        r0.x *= inv0; r0.y *= inv0; r0.z *= inv0; r0.w *= inv0;
        r1.x *= inv1; r1.y *= inv1; r1.z *= inv1; r1.w *= inv1;
        ((float4*)wsSlot)[t] = r0;                 // half0: seg s0
        ((float4*)(wsSlot + DLOC))[t] = r1;        // half1: seg s0+1
    }
}

__global__ __launch_bounds__(256) void seg_mean_kernel(
    const float4* __restrict__ ff, const float4* __restrict__ fc,
    const int* __restrict__ len_f, const int* __restrict__ len_c,
    float* __restrict__ ws, int fineBlocks)
{
    __shared__ int   s_cum[NSEG];
    __shared__ float s_inv[NSEG];
    __shared__ float lds[2048];
    const bool fine = (int)blockIdx.x < fineBlocks;
    const int* len = fine ? len_f : len_c;
    if (threadIdx.x == 0) {
        int c = 0;
        for (int i = 0; i < NSEG; ++i) {
            int l = len[i];
            c += l;
            s_cum[i] = c;
            s_inv[i] = 1.0f / (float)l;
        }
    }
    __syncthreads();

    if (fine) {
        const int b = (int)blockIdx.x;
        run_side<FINE_ITERS, 5, 31, 128>(ff, b, s_cum, s_inv, ws + b * 256, lds);
    } else {
        const int b = (int)blockIdx.x - fineBlocks;
        run_side<COARSE_ITERS, 6, 63, 256>(fc, b, s_cum, s_inv,
                                           ws + fineBlocks * 256 + b * 512, lds);
    }
}

// ---------------------------------------------------------------------------
// Slot reduction, rewritten (R3 post-mortem: serial LDS s0-walk + guarded
// loads made a ~32-block serial tail). Block b of seg_mean has s0(b)==s
// iff cum[s-1] <= b*R < cum[s]  ->  closed-form block range per segment.
// Two tight loops of UNGUARDED independent loads (half0 of blocks starting
// in seg, half1 of blocks starting in seg-1) -> fully pipelined.
// Blocks 0..15: fine seg -> out cols 256..383; 16..31: coarse -> cols 0..255.
// ---------------------------------------------------------------------------
__global__ __launch_bounds__(256) void reduce_kernel(
    const float* __restrict__ ws,
    const int* __restrict__ len_f, const int* __restrict__ len_c,
    float* __restrict__ out, int fineBlocks, int coarseBlocks)
{
    __shared__ int cum[NSEG + 1];
    const bool fine = (int)blockIdx.x < NSEG;
    const int seg = (int)blockIdx.x & 15;
    const int* len = fine ? len_f : len_c;
    if (threadIdx.x == 0) {
        int c = 0;
        cum[0] = 0;
        for (int i = 0; i < NSEG; ++i) { c += len[i]; cum[i + 1] = c; }
    }
    __syncthreads();

    const int D = fine ? 128 : 256;
    const int c = threadIdx.x;
    if (c >= D) return;

    const float* base = fine ? ws : ws + fineBlocks * 256;
    const int shift = fine ? 8 : 6;            // rows per window: 256 / 64
    const int slotSize = 2 * D;

    // blocks whose window STARTS in segment s: [bLo(s), bHi(s)] inclusive
    auto bLo = [&](int s) { return (cum[s] + (1 << shift) - 1) >> shift; };
    auto bHi = [&](int s) { return (cum[s + 1] - 1) >> shift; };

    float acc = 0.f;
    {   // half0 of blocks starting in `seg`
        const int lo = bLo(seg), hi = bHi(seg);
        for (int b = lo; b <= hi; ++b)
            acc += base[b * slotSize + c];
    }
    if (seg >= 1) {  // half1 of blocks starting in `seg-1` (non-crossers add 0)
        const int lo = bLo(seg - 1), hi = bHi(seg - 1);
        for (int b = lo; b <= hi; ++b)
            acc += base[b * slotSize + D + c];
    }
    out[seg * OUT_COLS + (fine ? 256 + c : c)] = acc;
}

extern "C" void kernel_launch(void* const* d_in, const int* in_sizes, int n_in,
                              void* d_out, int out_size, void* d_ws, size_t ws_size,
                              hipStream_t stream) {
    const float4* ff = (const float4*)d_in[0];   // feats_f [524288,128] f32
    const float4* fc = (const float4*)d_in[1];   // feats_c [32768,256]  f32
    const int* lf = (const int*)d_in[2];         // lengths_f [16] i32
    const int* lc = (const int*)d_in[3];         // lengths_c [16] i32
    float* out = (float*)d_out;                  // [16,384] f32

    const int NF4 = in_sizes[0] / 4;             // 16,777,216 float4
    const int NC4 = in_sizes[1] / 4;             //  2,097,152 float4
    const int fineBlocks   = NF4 / (256 * FINE_ITERS);    // 2048
    const int coarseBlocks = NC4 / (256 * COARSE_ITERS);  // 512

    seg_mean_kernel<<<fineBlocks + coarseBlocks, 256, 0, stream>>>(
        ff, fc, lf, lc, (float*)d_ws, fineBlocks);

    reduce_kernel<<<2 * NSEG, 256, 0, stream>>>(
        (const float*)d_ws, lf, lc, out, fineBlocks, coarseBlocks);
}